// Round 1
// baseline (4213.667 us; speedup 1.0000x reference)
//
#include <hip/hip_runtime.h>

#define FDIM 20
#define NSLOPE 0.2f
#define FORD_NEGINF 0x007FFFFFu   // ford(-inf)

// order-preserving float <-> uint mapping for atomicMax on floats
__device__ __forceinline__ unsigned ford(float f) {
    unsigned u = __float_as_uint(f);
    return (u & 0x80000000u) ? ~u : (u | 0x80000000u);
}
__device__ __forceinline__ float funord(unsigned u) {
    return (u & 0x80000000u) ? __uint_as_float(u & 0x7fffffffu)
                             : __uint_as_float(~u);
}

__device__ __forceinline__ float lrelu(float v) {
    return (v > 0.f) ? v : NSLOPE * v;
}

// Layer-1 node init: alpha_src/dst are rank-1 (h1 = x * W1row), so
// as[i] = x[i] * (W1·a_src1), ad[i] = x[i] * (W1·a_dst1).
__global__ void k_node_l1(const float* __restrict__ x,
                          const float* __restrict__ W1,
                          const float* __restrict__ a_src,
                          const float* __restrict__ a_dst,
                          float* __restrict__ AS, float* __restrict__ AD,
                          float* __restrict__ S, float* __restrict__ DEN,
                          unsigned* __restrict__ EMAX, int N)
{
    int i = blockIdx.x * blockDim.x + threadIdx.x;
    if (i >= N) return;
    float cs = 0.f, cd = 0.f;
#pragma unroll
    for (int f = 0; f < FDIM; ++f) {
        float w = W1[f];
        cs += w * a_src[f];
        cd += w * a_dst[f];
    }
    float xv = x[i];
    AS[i] = xv * cs;
    AD[i] = xv * cd;
    S[i]   = 0.f;
    DEN[i] = 0.f;
    EMAX[i] = FORD_NEGINF;
}

// Segment-max over destination nodes (shared by both layers).
__global__ void k_edge_max(const int* __restrict__ ei, int E, int N,
                           const float* __restrict__ AS,
                           const float* __restrict__ AD,
                           unsigned* __restrict__ EMAX)
{
    int e = blockIdx.x * blockDim.x + threadIdx.x;
    if (e >= E + N) return;
    int s, d;
    if (e < E) { s = ei[e]; d = ei[E + e]; }
    else       { s = d = e - E; }            // virtual self-loop
    float v = lrelu(AS[s] + AD[d]);
    atomicMax(EMAX + d, ford(v));
}

// Layer-1 edge accumulate: rank-1 trick -> only 2 scalar atomics per edge.
__global__ void k_edge_acc1(const int* __restrict__ ei, int E, int N,
                            const float* __restrict__ x,
                            const float* __restrict__ AS,
                            const float* __restrict__ AD,
                            const unsigned* __restrict__ EMAX,
                            float* __restrict__ DEN, float* __restrict__ S)
{
    int e = blockIdx.x * blockDim.x + threadIdx.x;
    if (e >= E + N) return;
    int s, d;
    if (e < E) { s = ei[e]; d = ei[E + e]; }
    else       { s = d = e - E; }
    float v = lrelu(AS[s] + AD[d]);
    float w = __expf(v - funord(EMAX[d]));
    unsafeAtomicAdd(DEN + d, w);
    unsafeAtomicAdd(S + d, w * x[s]);
}

// Layer-1 epilogue (relu(S/den * W1 + b1)) fused with layer-2 h = t @ W2,
// alpha computation, and per-node softmax-state reset for layer 2.
__global__ void k_node_l2(const float* __restrict__ W1,
                          const float* __restrict__ b1,
                          const float* __restrict__ W2,
                          const float* __restrict__ a_src2,
                          const float* __restrict__ a_dst2,
                          const float* __restrict__ S,
                          float* __restrict__ DEN,
                          unsigned* __restrict__ EMAX,
                          float* __restrict__ H,
                          float* __restrict__ ACC,
                          float* __restrict__ AS, float* __restrict__ AD,
                          int N)
{
    __shared__ float sW2[FDIM * FDIM];
    __shared__ float sW1[FDIM], sb1[FDIM], sas[FDIM], sad[FDIM];
    for (int t = threadIdx.x; t < FDIM * FDIM; t += blockDim.x) sW2[t] = W2[t];
    if (threadIdx.x < FDIM) {
        sW1[threadIdx.x] = W1[threadIdx.x];
        sb1[threadIdx.x] = b1[threadIdx.x];
        sas[threadIdx.x] = a_src2[threadIdx.x];
        sad[threadIdx.x] = a_dst2[threadIdx.x];
    }
    __syncthreads();
    int i = blockIdx.x * blockDim.x + threadIdx.x;
    if (i >= N) return;
    float inv = 1.f / (DEN[i] + 1e-16f);
    float sv = S[i] * inv;
    float t[FDIM];
#pragma unroll
    for (int k = 0; k < FDIM; ++k) {
        float v = sv * sW1[k] + sb1[k];
        t[k] = (v > 0.f) ? v : 0.f;          // relu(layer-1 output)
    }
    float as = 0.f, ad = 0.f;
    size_t base = (size_t)i * FDIM;
#pragma unroll
    for (int f = 0; f < FDIM; ++f) {
        float h = 0.f;
#pragma unroll
        for (int k = 0; k < FDIM; ++k) h += t[k] * sW2[k * FDIM + f];
        H[base + f]   = h;
        ACC[base + f] = 0.f;                 // zero layer-2 accumulator row
        as += h * sas[f];
        ad += h * sad[f];
    }
    AS[i] = as; AD[i] = ad;
    DEN[i]  = 0.f;
    EMAX[i] = FORD_NEGINF;
}

// Layer-2 edge accumulate: full 20-wide row scatter (21 atomics/edge).
__global__ void k_edge_acc2(const int* __restrict__ ei, int E, int N,
                            const float* __restrict__ H,
                            const float* __restrict__ AS,
                            const float* __restrict__ AD,
                            const unsigned* __restrict__ EMAX,
                            float* __restrict__ DEN,
                            float* __restrict__ ACC)
{
    int e = blockIdx.x * blockDim.x + threadIdx.x;
    if (e >= E + N) return;
    int s, d;
    if (e < E) { s = ei[e]; d = ei[E + e]; }
    else       { s = d = e - E; }
    float v = lrelu(AS[s] + AD[d]);
    float w = __expf(v - funord(EMAX[d]));
    unsafeAtomicAdd(DEN + d, w);
    const float* hs = H + (size_t)s * FDIM;
    float* od = ACC + (size_t)d * FDIM;
#pragma unroll
    for (int f = 0; f < FDIM; ++f)
        unsafeAtomicAdd(od + f, w * hs[f]);
}

// Layer-2 epilogue + relu + linear head, fused.
__global__ void k_final(const float* __restrict__ b2,
                        const float* __restrict__ Wl,
                        const float* __restrict__ bl,
                        const float* __restrict__ ACC,
                        const float* __restrict__ DEN,
                        float* __restrict__ out, int N)
{
    int i = blockIdx.x * blockDim.x + threadIdx.x;
    if (i >= N) return;
    float inv = 1.f / (DEN[i] + 1e-16f);
    float acc = 0.f;
    size_t base = (size_t)i * FDIM;
#pragma unroll
    for (int k = 0; k < FDIM; ++k) {
        float v = ACC[base + k] * inv + b2[k];
        v = (v > 0.f) ? v : 0.f;
        acc += v * Wl[k];
    }
    out[i] = acc + bl[0];
}

extern "C" void kernel_launch(void* const* d_in, const int* in_sizes, int n_in,
                              void* d_out, int out_size, void* d_ws, size_t ws_size,
                              hipStream_t stream)
{
    const float* x      = (const float*)d_in[0];
    const int*   ei     = (const int*)d_in[1];
    const float* W1     = (const float*)d_in[2];
    const float* a_src1 = (const float*)d_in[3];
    const float* a_dst1 = (const float*)d_in[4];
    const float* b1     = (const float*)d_in[5];
    const float* W2     = (const float*)d_in[6];
    const float* a_src2 = (const float*)d_in[7];
    const float* a_dst2 = (const float*)d_in[8];
    const float* b2     = (const float*)d_in[9];
    const float* Wl     = (const float*)d_in[10];
    const float* bl     = (const float*)d_in[11];
    float* out = (float*)d_out;

    const int N = in_sizes[0];
    const int E = in_sizes[1] / 2;

    float* ws  = (float*)d_ws;
    float* H   = ws;                          // [N*20] layer-2 h
    float* ACC = H + (size_t)N * FDIM;        // [N*20] layer-2 accum
    float* AS  = ACC + (size_t)N * FDIM;      // [N]
    float* AD  = AS + N;                      // [N]
    float* S   = AD + N;                      // [N] layer-1 scalar accum
    float* DEN = S + N;                       // [N]
    unsigned* EMAX = (unsigned*)(DEN + N);    // [N]

    const int BLK = 256;
    const int nb_n = (N + BLK - 1) / BLK;
    const int nb_e = (E + N + BLK - 1) / BLK;

    k_node_l1 <<<nb_n, BLK, 0, stream>>>(x, W1, a_src1, a_dst1, AS, AD, S, DEN, EMAX, N);
    k_edge_max<<<nb_e, BLK, 0, stream>>>(ei, E, N, AS, AD, EMAX);
    k_edge_acc1<<<nb_e, BLK, 0, stream>>>(ei, E, N, x, AS, AD, EMAX, DEN, S);
    k_node_l2 <<<nb_n, BLK, 0, stream>>>(W1, b1, W2, a_src2, a_dst2, S, DEN, EMAX, H, ACC, AS, AD, N);
    k_edge_max<<<nb_e, BLK, 0, stream>>>(ei, E, N, AS, AD, EMAX);
    k_edge_acc2<<<nb_e, BLK, 0, stream>>>(ei, E, N, H, AS, AD, EMAX, DEN, ACC);
    k_final   <<<nb_n, BLK, 0, stream>>>(b2, Wl, bl, ACC, DEN, out, N);
}

// Round 2
// 682.797 us; speedup vs baseline: 6.1712x; 6.1712x over previous
//
#include <hip/hip_runtime.h>

#define FDIM 20
#define NSLOPE 0.2f

__device__ __forceinline__ float lrelu(float v) { return v > 0.f ? v : NSLOPE * v; }

// 1) per-node init: rank-1 layer-1 alphas (h1 = x*W1row) + zero histogram
__global__ void k_init(const float* __restrict__ x,
                       const float* __restrict__ W1,
                       const float* __restrict__ a_src,
                       const float* __restrict__ a_dst,
                       float* __restrict__ AS, float* __restrict__ AD,
                       int* __restrict__ counts, int N)
{
    int i = blockIdx.x * blockDim.x + threadIdx.x;
    if (i >= N) return;
    float cs = 0.f, cd = 0.f;
#pragma unroll
    for (int f = 0; f < FDIM; ++f) { float w = W1[f]; cs += w * a_src[f]; cd += w * a_dst[f]; }
    float xv = x[i];
    AS[i] = xv * cs;
    AD[i] = xv * cd;
    counts[i] = 0;
}

// 2) in-degree histogram
__global__ void k_hist(const int* __restrict__ ei, int E, int* __restrict__ counts)
{
    int e = blockIdx.x * blockDim.x + threadIdx.x;
    if (e >= E) return;
    atomicAdd(counts + ei[E + e], 1);
}

// 3) block-local exclusive scan (256/block) + block totals
__global__ void k_scan1(const int* __restrict__ counts, int N,
                        int* __restrict__ ex, int* __restrict__ partial)
{
    __shared__ int s[256];
    int t = threadIdx.x;
    int i = blockIdx.x * 256 + t;
    int v = (i < N) ? counts[i] : 0;
    s[t] = v; __syncthreads();
    for (int o = 1; o < 256; o <<= 1) {
        int tmp = (t >= o) ? s[t - o] : 0; __syncthreads();
        s[t] += tmp; __syncthreads();
    }
    if (i < N) ex[i] = s[t] - v;
    if (t == 255) partial[blockIdx.x] = s[255];
}

// 4) exclusive scan of block totals (NB <= 512, single block)
__global__ void k_scan2(int* __restrict__ partial, int NB)
{
    __shared__ int s[512];
    int t = threadIdx.x;
    int v = (t < NB) ? partial[t] : 0;
    s[t] = v; __syncthreads();
    for (int o = 1; o < 512; o <<= 1) {
        int tmp = (t >= o) ? s[t - o] : 0; __syncthreads();
        s[t] += tmp; __syncthreads();
    }
    if (t < NB) partial[t] = s[t] - v;
}

// 5) finalize rowptr, init scatter cursors
__global__ void k_scan3(int* __restrict__ rowptr, const int* __restrict__ partial,
                        int* __restrict__ cursor, int N, int E)
{
    int i = blockIdx.x * blockDim.x + threadIdx.x;
    if (i >= N) return;
    int v = rowptr[i] + partial[i >> 8];    // i>>8 matches k_scan1's 256-blocking
    rowptr[i] = v;
    cursor[i] = v;
    if (i == 0) rowptr[N] = E;
}

// 6) fill CSR src lists (one int atomic per edge)
__global__ void k_scatter(const int* __restrict__ ei, int E,
                          int* __restrict__ cursor, int* __restrict__ csr)
{
    int e = blockIdx.x * blockDim.x + threadIdx.x;
    if (e >= E) return;
    int s = ei[e], d = ei[E + e];
    int pos = atomicAdd(cursor + d, 1);
    csr[pos] = s;
}

// 7) layer-1 gather (wave per node): softmax over in-edges (scalar rank-1
// accumulation) + fused epilogue: relu(.. )@W2 -> H, alpha2 src/dst.
__global__ void k_gat1(const int* __restrict__ rowptr, const int* __restrict__ csr,
                       const float* __restrict__ x,
                       const float* __restrict__ AS, const float* __restrict__ AD,
                       const float* __restrict__ W1, const float* __restrict__ b1,
                       const float* __restrict__ W2,
                       const float* __restrict__ a_src2, const float* __restrict__ a_dst2,
                       float* __restrict__ H,
                       float* __restrict__ AS2, float* __restrict__ AD2, int N)
{
    __shared__ float sW1[FDIM], sb1[FDIM], sW2[FDIM * FDIM], sas[FDIM], sad[FDIM];
    for (int t = threadIdx.x; t < FDIM * FDIM; t += blockDim.x) sW2[t] = W2[t];
    if (threadIdx.x < FDIM) {
        sW1[threadIdx.x] = W1[threadIdx.x];
        sb1[threadIdx.x] = b1[threadIdx.x];
        sas[threadIdx.x] = a_src2[threadIdx.x];
        sad[threadIdx.x] = a_dst2[threadIdx.x];
    }
    __syncthreads();
    int wv = (blockIdx.x * blockDim.x + threadIdx.x) >> 6;   // wave id = node id
    int lane = threadIdx.x & 63;
    if (wv >= N) return;
    int beg = rowptr[wv];
    int deg = rowptr[wv + 1] - beg;                          // +1 virtual self-loop
    float ad = AD[wv];
    float m = -1e30f;
    for (int i = lane; i <= deg; i += 64) {
        int s = (i < deg) ? csr[beg + i] : wv;
        m = fmaxf(m, lrelu(AS[s] + ad));
    }
#pragma unroll
    for (int o = 32; o > 0; o >>= 1) m = fmaxf(m, __shfl_xor(m, o));
    float den = 0.f, sx = 0.f;
    for (int i = lane; i <= deg; i += 64) {
        int s = (i < deg) ? csr[beg + i] : wv;
        float w = __expf(lrelu(AS[s] + ad) - m);
        den += w;
        sx += w * x[s];
    }
#pragma unroll
    for (int o = 32; o > 0; o >>= 1) { den += __shfl_xor(den, o); sx += __shfl_xor(sx, o); }
    float sv = sx / (den + 1e-16f);
    // epilogue: t = relu(sv*W1 + b1); h = t @ W2; lanes 0..19 own one feature
    float h = 0.f;
    if (lane < FDIM) {
#pragma unroll
        for (int k = 0; k < FDIM; ++k) {
            float t = sv * sW1[k] + sb1[k];
            t = t > 0.f ? t : 0.f;
            h += t * sW2[k * FDIM + lane];
        }
        H[(size_t)wv * FDIM + lane] = h;
    }
    float pas = (lane < FDIM) ? h * sas[lane] : 0.f;
    float pad2 = (lane < FDIM) ? h * sad[lane] : 0.f;
#pragma unroll
    for (int o = 32; o > 0; o >>= 1) { pas += __shfl_xor(pas, o); pad2 += __shfl_xor(pad2, o); }
    if (lane == 0) { AS2[wv] = pas; AD2[wv] = pad2; }
}

// 8) layer-2 gather (wave per node): softmax + 20-wide weighted H gather,
// fused epilogue: relu(acc/den + b2) @ Wl + bl -> out.
__global__ void k_gat2(const int* __restrict__ rowptr, const int* __restrict__ csr,
                       const float* __restrict__ H,
                       const float* __restrict__ AS, const float* __restrict__ AD,
                       const float* __restrict__ b2, const float* __restrict__ Wl,
                       const float* __restrict__ bl,
                       float* __restrict__ out, int N)
{
    int wv = (blockIdx.x * blockDim.x + threadIdx.x) >> 6;
    int lane = threadIdx.x & 63;
    if (wv >= N) return;
    int beg = rowptr[wv];
    int deg = rowptr[wv + 1] - beg;
    float ad = AD[wv];
    float m = -1e30f;
    for (int i = lane; i <= deg; i += 64) {
        int s = (i < deg) ? csr[beg + i] : wv;
        m = fmaxf(m, lrelu(AS[s] + ad));
    }
#pragma unroll
    for (int o = 32; o > 0; o >>= 1) m = fmaxf(m, __shfl_xor(m, o));
    float den = 0.f;
    float acc[FDIM];
#pragma unroll
    for (int j = 0; j < FDIM; ++j) acc[j] = 0.f;
    for (int i = lane; i <= deg; i += 64) {
        int s = (i < deg) ? csr[beg + i] : wv;
        float w = __expf(lrelu(AS[s] + ad) - m);
        den += w;
        const float4* hp = (const float4*)(H + (size_t)s * FDIM);
#pragma unroll
        for (int q = 0; q < 5; ++q) {
            float4 h4 = hp[q];
            acc[q * 4 + 0] += w * h4.x;
            acc[q * 4 + 1] += w * h4.y;
            acc[q * 4 + 2] += w * h4.z;
            acc[q * 4 + 3] += w * h4.w;
        }
    }
#pragma unroll
    for (int o = 32; o > 0; o >>= 1) {
        den += __shfl_xor(den, o);
#pragma unroll
        for (int j = 0; j < FDIM; ++j) acc[j] += __shfl_xor(acc[j], o);
    }
    if (lane == 0) {
        float inv = 1.f / (den + 1e-16f);
        float r = 0.f;
#pragma unroll
        for (int k = 0; k < FDIM; ++k) {
            float v = acc[k] * inv + b2[k];
            v = v > 0.f ? v : 0.f;
            r += v * Wl[k];
        }
        out[wv] = r + bl[0];
    }
}

extern "C" void kernel_launch(void* const* d_in, const int* in_sizes, int n_in,
                              void* d_out, int out_size, void* d_ws, size_t ws_size,
                              hipStream_t stream)
{
    const float* x      = (const float*)d_in[0];
    const int*   ei     = (const int*)d_in[1];
    const float* W1     = (const float*)d_in[2];
    const float* a_src1 = (const float*)d_in[3];
    const float* a_dst1 = (const float*)d_in[4];
    const float* b1     = (const float*)d_in[5];
    const float* W2     = (const float*)d_in[6];
    const float* a_src2 = (const float*)d_in[7];
    const float* a_dst2 = (const float*)d_in[8];
    const float* b2     = (const float*)d_in[9];
    const float* Wl     = (const float*)d_in[10];
    const float* bl     = (const float*)d_in[11];
    float* out = (float*)d_out;

    const int N = in_sizes[0];
    const int E = in_sizes[1] / 2;
    const int NB = (N + 255) / 256;          // scan blocking (must be <= 512)

    // workspace layout
    float* ws   = (float*)d_ws;
    float* H    = ws;                         // [N*20]
    float* AS   = H + (size_t)N * FDIM;       // [N]  layer-1 alpha_src
    float* AD   = AS + N;                     // [N]  layer-1 alpha_dst
    float* AS2  = AD + N;                     // [N]  layer-2 alpha_src
    float* AD2  = AS2 + N;                    // [N]  layer-2 alpha_dst
    int* rowptr = (int*)(AD2 + N);            // [N+1]
    int* counts = rowptr + (N + 1);           // [N]
    int* cursor = counts + N;                 // [N]
    int* partial= cursor + N;                 // [512]
    int* csr    = partial + 512;              // [E]

    const int BLK = 256;
    const int nb_n = (N + BLK - 1) / BLK;
    const int nb_e = (E + BLK - 1) / BLK;
    const int nb_w = ((size_t)N * 64 + BLK - 1) / BLK;   // wave-per-node kernels

    k_init   <<<nb_n, BLK, 0, stream>>>(x, W1, a_src1, a_dst1, AS, AD, counts, N);
    k_hist   <<<nb_e, BLK, 0, stream>>>(ei, E, counts);
    k_scan1  <<<NB,   256, 0, stream>>>(counts, N, rowptr, partial);
    k_scan2  <<<1,    512, 0, stream>>>(partial, NB);
    k_scan3  <<<nb_n, BLK, 0, stream>>>(rowptr, partial, cursor, N, E);
    k_scatter<<<nb_e, BLK, 0, stream>>>(ei, E, cursor, csr);
    k_gat1   <<<nb_w, BLK, 0, stream>>>(rowptr, csr, x, AS, AD, W1, b1, W2,
                                        a_src2, a_dst2, H, AS2, AD2, N);
    k_gat2   <<<nb_w, BLK, 0, stream>>>(rowptr, csr, H, AS2, AD2, b2, Wl, bl, out, N);
}